// Round 5
// baseline (377.121 us; speedup 1.0000x reference)
//
#include <hip/hip_runtime.h>

#define N_NODES 100000
#define E_EDGES 1600000
#define D 128
#define AP 132   // padded LDS pitch for fallback fp32 gemm
#define ASTR 136 // bf16 elems per LDS row in MFMA gemm (272 B)

typedef short s16x8 __attribute__((ext_vector_type(8)));
typedef float f32x4 __attribute__((ext_vector_type(4)));

__device__ __forceinline__ unsigned short f2bf(float f) {
    union { float f; unsigned u; } v;
    v.f = f;
    unsigned r = v.u + 0x7FFFu + ((v.u >> 16) & 1u);  // RNE
    return (unsigned short)(r >> 16);
}

__device__ __forceinline__ float bf2f(unsigned short u) {
    union { unsigned u; float f; } v;
    v.u = ((unsigned)u) << 16;
    return v.f;
}

__device__ __forceinline__ float lrelu(float v) {
    return v >= 0.0f ? v : 0.01f * v;
}

// ==================== x -> bf16 table =========================================
__global__ __launch_bounds__(256) void xconv_kernel(
    const float* __restrict__ x, unsigned short* __restrict__ xbf) {
    int idx = blockIdx.x * 256 + threadIdx.x;
    const float4* xp = (const float4*)(x) + (size_t)idx * 2;
    float4 a = xp[0], b = xp[1];
    ushort4 lo, hi;
    lo.x = f2bf(a.x); lo.y = f2bf(a.y); lo.z = f2bf(a.z); lo.w = f2bf(a.w);
    hi.x = f2bf(b.x); hi.y = f2bf(b.y); hi.z = f2bf(b.z); hi.w = f2bf(b.w);
    ushort4* dp = (ushort4*)(xbf) + (size_t)idx * 2;
    dp[0] = lo; dp[1] = hi;
}

// ===================== CSR build (counting sort by dst) =======================
// hist + rank in one pass; counters padded to `stride` ints (64 B when 16) so
// atomic targets land in distinct sectors (16x more parallel atomic units).
__global__ __launch_bounds__(256) void hist_kernel(
    const int* __restrict__ dst, int* __restrict__ cnt,
    unsigned char* __restrict__ rank, int E, int stride) {
    int e = blockIdx.x * 256 + threadIdx.x;
    if (e < E) rank[e] = (unsigned char)atomicAdd(&cnt[(size_t)dst[e] * stride], 1);
}

// scanA: per-block exclusive scan of padded counters -> off[]; block sums out.
__global__ __launch_bounds__(256) void scanA_kernel(
    const int* __restrict__ cnt, int* __restrict__ off,
    int* __restrict__ bsum, int n, int stride) {
    __shared__ int tmp[256];
    int gid = blockIdx.x * 256 + threadIdx.x;
    int v = (gid < n) ? cnt[(size_t)gid * stride] : 0;
    tmp[threadIdx.x] = v;
    __syncthreads();
    for (int ofs = 1; ofs < 256; ofs <<= 1) {
        int t = (threadIdx.x >= ofs) ? tmp[threadIdx.x - ofs] : 0;
        __syncthreads();
        tmp[threadIdx.x] += t;
        __syncthreads();
    }
    int incl = tmp[threadIdx.x];
    if (gid < n) off[gid] = incl - v;
    if (threadIdx.x == 255) bsum[blockIdx.x] = incl;
}

__global__ __launch_bounds__(512) void scanB_kernel(int* __restrict__ bsum, int nb) {
    __shared__ int tmp[512];
    int v = (threadIdx.x < nb) ? bsum[threadIdx.x] : 0;
    tmp[threadIdx.x] = v;
    __syncthreads();
    for (int ofs = 1; ofs < 512; ofs <<= 1) {
        int t = (threadIdx.x >= ofs) ? tmp[threadIdx.x - ofs] : 0;
        __syncthreads();
        tmp[threadIdx.x] += t;
        __syncthreads();
    }
    if (threadIdx.x < nb) bsum[threadIdx.x] = tmp[threadIdx.x] - v;
}

// scanC: off[gid] += block-offset (in place); off[n] = E.
__global__ __launch_bounds__(256) void scanC_kernel(
    const int* __restrict__ bsumExcl, int* __restrict__ off, int n, int E) {
    int gid = blockIdx.x * 256 + threadIdx.x;
    if (gid < n) off[gid] += bsumExcl[gid >> 8];
    if (gid == 0) off[n] = E;
}

// atomic-free fill: one packed 8B store per edge
__global__ __launch_bounds__(256) void fill_kernel(
    const int* __restrict__ src, const int* __restrict__ dst,
    const float* __restrict__ ea, const int* __restrict__ off,
    const unsigned char* __restrict__ rank, int2* __restrict__ csr, int E) {
    int e = blockIdx.x * 256 + threadIdx.x;
    if (e >= E) return;
    int d = dst[e];
    int pos = off[d] + (int)rank[e];
    csr[pos] = make_int2(src[e], __float_as_int(ea[e]));
}

// ====== Fused gather + MFMA GEMM ==============================================
// Block: 256 thr = 4 waves, 64 nodes x 128 outs. Phase 1: wave wv gathers h for
// nodes [n0+wv*16, n0+wv*16+16) in registers (half-wave per edge) and writes the
// bf16 (x+h)/(x*h) A-tiles straight to LDS — h never touches global memory.
// Phase 2: 16x16x32 bf16 MFMA with per-wave-persistent B fragments (R3-proven).
__global__ __launch_bounds__(256, 4) void fused_gemm_kernel(
    const unsigned short* __restrict__ xbf, const int2* __restrict__ csr,
    const int* __restrict__ off, const unsigned short* __restrict__ Wswz,
    const float* __restrict__ b1, const float* __restrict__ b2,
    float* __restrict__ out) {
    __shared__ unsigned short A[2][64 * ASTR];

    const int n0 = blockIdx.x * 64;
    const int t = threadIdx.x;
    const int lane = t & 63;
    const int wv = t >> 6;
    const int half = lane >> 5;
    const int li = lane & 31;

    // Preload persistent B fragments + biases (independent of gather).
    s16x8 Bf[2][2][4];
    float bb1[2], bb2[2];
#pragma unroll
    for (int ci = 0; ci < 2; ++ci) {
        int ct = wv + ci * 4;
        bb1[ci] = b1[ct * 16 + (lane & 15)];
        bb2[ci] = b2[ct * 16 + (lane & 15)];
#pragma unroll
        for (int mat = 0; mat < 2; ++mat)
#pragma unroll
            for (int ks = 0; ks < 4; ++ks)
                Bf[ci][mat][ks] = *(const s16x8*)(
                    Wswz + ((size_t)(((mat * 4 + ks) * 8 + ct) * 64 + lane)) * 8);
    }

    // ---- Phase 1: gather h per node, build A tiles.
    for (int j = 0; j < 16; ++j) {
        int row = wv * 16 + j;
        int node = n0 + row;
        float4 hacc = make_float4(0.f, 0.f, 0.f, 0.f);
        if (node < N_NODES) {
            int beg = off[node];
            int end = off[node + 1];
            float4 acc1 = make_float4(0.f, 0.f, 0.f, 0.f);
            int i = beg + half;
            for (; i + 2 < end; i += 4) {   // 2 edges per half in flight
                int2 p0 = csr[i];
                int2 p1 = csr[i + 2];
                float a0 = __int_as_float(p0.y);
                float a1 = __int_as_float(p1.y);
                ushort4 v0 = ((const ushort4*)(xbf + (size_t)p0.x * D))[li];
                ushort4 v1 = ((const ushort4*)(xbf + (size_t)p1.x * D))[li];
                hacc.x += a0 * bf2f(v0.x); hacc.y += a0 * bf2f(v0.y);
                hacc.z += a0 * bf2f(v0.z); hacc.w += a0 * bf2f(v0.w);
                acc1.x += a1 * bf2f(v1.x); acc1.y += a1 * bf2f(v1.y);
                acc1.z += a1 * bf2f(v1.z); acc1.w += a1 * bf2f(v1.w);
            }
            if (i < end) {
                int2 p0 = csr[i];
                float a0 = __int_as_float(p0.y);
                ushort4 v0 = ((const ushort4*)(xbf + (size_t)p0.x * D))[li];
                hacc.x += a0 * bf2f(v0.x); hacc.y += a0 * bf2f(v0.y);
                hacc.z += a0 * bf2f(v0.z); hacc.w += a0 * bf2f(v0.w);
            }
            hacc.x += acc1.x; hacc.y += acc1.y;
            hacc.z += acc1.z; hacc.w += acc1.w;
        }
        // combine the two halves (all lanes participate)
        float4 oth;
        oth.x = __shfl(hacc.x, lane ^ 32);
        oth.y = __shfl(hacc.y, lane ^ 32);
        oth.z = __shfl(hacc.z, lane ^ 32);
        oth.w = __shfl(hacc.w, lane ^ 32);
        hacc.x += oth.x; hacc.y += oth.y; hacc.z += oth.z; hacc.w += oth.w;

        if (half == 0) {
            ushort4 av, mv;
            if (node < N_NODES) {
                ushort4 xu = ((const ushort4*)(xbf + (size_t)node * D))[li];
                float4 xv = make_float4(bf2f(xu.x), bf2f(xu.y), bf2f(xu.z), bf2f(xu.w));
                av.x = f2bf(xv.x + hacc.x); av.y = f2bf(xv.y + hacc.y);
                av.z = f2bf(xv.z + hacc.z); av.w = f2bf(xv.w + hacc.w);
                mv.x = f2bf(xv.x * hacc.x); mv.y = f2bf(xv.y * hacc.y);
                mv.z = f2bf(xv.z * hacc.z); mv.w = f2bf(xv.w * hacc.w);
            } else {
                av = make_ushort4(0, 0, 0, 0);
                mv = make_ushort4(0, 0, 0, 0);
            }
            *(ushort4*)&A[0][row * ASTR + li * 4] = av;
            *(ushort4*)&A[1][row * ASTR + li * 4] = mv;
        }
    }

    __syncthreads();

    // ---- Phase 2: MFMA.
    const int quad = lane >> 4;
    const int kq = quad * 8;

#pragma unroll
    for (int mt = 0; mt < 4; ++mt) {
        f32x4 acc[2][2];
#pragma unroll
        for (int ci = 0; ci < 2; ++ci)
#pragma unroll
            for (int p = 0; p < 2; ++p) acc[ci][p] = (f32x4){0.f, 0.f, 0.f, 0.f};

        const int arow = mt * 16 + (lane & 15);
#pragma unroll
        for (int ks = 0; ks < 4; ++ks) {
            s16x8 a0 = *(const s16x8*)&A[0][arow * ASTR + ks * 32 + kq];
            s16x8 a1 = *(const s16x8*)&A[1][arow * ASTR + ks * 32 + kq];
#pragma unroll
            for (int ci = 0; ci < 2; ++ci) {
                acc[ci][0] = __builtin_amdgcn_mfma_f32_16x16x32_bf16(
                    a0, Bf[ci][0][ks], acc[ci][0], 0, 0, 0);
                acc[ci][1] = __builtin_amdgcn_mfma_f32_16x16x32_bf16(
                    a1, Bf[ci][1][ks], acc[ci][1], 0, 0, 0);
            }
        }

        // C/D layout: col=lane&15, row=quad*4+reg (m89-verified).
#pragma unroll
        for (int ci = 0; ci < 2; ++ci) {
            int oc = (wv + ci * 4) * 16 + (lane & 15);
#pragma unroll
            for (int r = 0; r < 4; ++r) {
                int node = n0 + mt * 16 + quad * 4 + r;
                if (node < N_NODES) {
                    float v = lrelu(acc[ci][0][r] + bb1[ci])
                            + lrelu(acc[ci][1][r] + bb2[ci]);
                    out[(size_t)node * D + oc] = v;
                }
            }
        }
    }
}

// ========== Gather (fp32 x) — tier-1 fallback, packed csr =====================
__global__ __launch_bounds__(256) void gather_f32_kernel(
    const float* __restrict__ x, const int2* __restrict__ csr,
    const int* __restrict__ off, float* __restrict__ h) {
    int node = blockIdx.x * 4 + (threadIdx.x >> 6);
    int lane = threadIdx.x & 63;
    int beg = off[node];
    int end = off[node + 1];
    float2 acc0 = make_float2(0.f, 0.f);
    float2 acc1 = make_float2(0.f, 0.f);
    int e = beg;
    for (; e + 1 < end; e += 2) {
        int2 p0 = csr[e];
        int2 p1 = csr[e + 1];
        float a0 = __int_as_float(p0.y);
        float a1 = __int_as_float(p1.y);
        float2 v0 = ((const float2*)(x + (size_t)p0.x * D))[lane];
        float2 v1 = ((const float2*)(x + (size_t)p1.x * D))[lane];
        acc0.x += a0 * v0.x; acc0.y += a0 * v0.y;
        acc1.x += a1 * v1.x; acc1.y += a1 * v1.y;
    }
    if (e < end) {
        int2 p0 = csr[e];
        float a0 = __int_as_float(p0.y);
        float2 v0 = ((const float2*)(x + (size_t)p0.x * D))[lane];
        acc0.x += a0 * v0.x; acc0.y += a0 * v0.y;
    }
    acc0.x += acc1.x; acc0.y += acc1.y;
    ((float2*)(h + (size_t)node * D))[lane] = acc0;
}

// ================== Tier-0 fallback: atomic scatter ===========================
__global__ __launch_bounds__(256) void scatter_kernel(
    const float* __restrict__ x, const int* __restrict__ src,
    const int* __restrict__ dst, const float* __restrict__ ea,
    float* __restrict__ h, int E) {
    int idx = blockIdx.x * 256 + threadIdx.x;
    int e = idx >> 5;
    int lane = idx & 31;
    if (e >= E) return;
    int s = src[e];
    int d = dst[e];
    float a = ea[e];
    float4 v = ((const float4*)(x + (size_t)s * D))[lane];
    float* hp = h + (size_t)d * D + lane * 4;
    atomicAdd(hp + 0, a * v.x);
    atomicAdd(hp + 1, a * v.y);
    atomicAdd(hp + 2, a * v.z);
    atomicAdd(hp + 3, a * v.w);
}

// ============== W pre-swizzle into B-fragment order, fp32 -> bf16 =============
__global__ __launch_bounds__(256) void wconv_kernel(
    const float* __restrict__ W1, const float* __restrict__ W2,
    unsigned short* __restrict__ Wswz) {
    int tid = blockIdx.x * 256 + threadIdx.x;
    if (tid >= 2 * 4 * 8 * 64) return;
    int lane = tid & 63;
    int ct   = (tid >> 6) & 7;
    int ks   = (tid >> 9) & 3;
    int mat  = tid >> 11;
    const float* W = mat ? W2 : W1;
    int o  = ct * 16 + (lane & 15);
    int k0 = ks * 32 + (lane >> 4) * 8;
    const float* sp = W + (size_t)o * D + k0;
    unsigned short* dp = Wswz + (size_t)tid * 8;
    ushort4 lo, hi;
    lo.x = f2bf(sp[0]); lo.y = f2bf(sp[1]); lo.z = f2bf(sp[2]); lo.w = f2bf(sp[3]);
    hi.x = f2bf(sp[4]); hi.y = f2bf(sp[5]); hi.z = f2bf(sp[6]); hi.w = f2bf(sp[7]);
    *(ushort4*)(dp + 0) = lo;
    *(ushort4*)(dp + 4) = hi;
}

// ============== Tier-1 MFMA GEMM (reads h from global) ========================
__global__ __launch_bounds__(256, 4) void mfma_gemm_kernel(
    const float* __restrict__ xf, const float* __restrict__ h,
    const unsigned short* __restrict__ Wswz,
    const float* __restrict__ b1, const float* __restrict__ b2,
    float* __restrict__ out) {
    __shared__ unsigned short A[2][64 * ASTR];

    const int n0 = blockIdx.x * 64;
    const int t = threadIdx.x;
    const int lane = t & 63;
    const int wv = t >> 6;

#pragma unroll
    for (int i = 0; i < 8; ++i) {
        int s = t + i * 256;
        int row = s >> 5;
        int c4 = s & 31;
        int srcrow = n0 + row;
        if (srcrow >= N_NODES) srcrow = N_NODES - 1;
        float4 xv = ((const float4*)(xf + (size_t)srcrow * D))[c4];
        float4 hv = ((const float4*)(h + (size_t)srcrow * D))[c4];
        ushort4 av, mv;
        av.x = f2bf(xv.x + hv.x); av.y = f2bf(xv.y + hv.y);
        av.z = f2bf(xv.z + hv.z); av.w = f2bf(xv.w + hv.w);
        mv.x = f2bf(xv.x * hv.x); mv.y = f2bf(xv.y * hv.y);
        mv.z = f2bf(xv.z * hv.z); mv.w = f2bf(xv.w * hv.w);
        *(ushort4*)&A[0][row * ASTR + c4 * 4] = av;
        *(ushort4*)&A[1][row * ASTR + c4 * 4] = mv;
    }

    s16x8 Bf[2][2][4];
    float bb1[2], bb2[2];
#pragma unroll
    for (int ci = 0; ci < 2; ++ci) {
        int ct = wv + ci * 4;
        bb1[ci] = b1[ct * 16 + (lane & 15)];
        bb2[ci] = b2[ct * 16 + (lane & 15)];
#pragma unroll
        for (int mat = 0; mat < 2; ++mat)
#pragma unroll
            for (int ks = 0; ks < 4; ++ks)
                Bf[ci][mat][ks] = *(const s16x8*)(
                    Wswz + ((size_t)(((mat * 4 + ks) * 8 + ct) * 64 + lane)) * 8);
    }

    __syncthreads();

    const int quad = lane >> 4;
    const int kq = quad * 8;

#pragma unroll
    for (int mt = 0; mt < 4; ++mt) {
        f32x4 acc[2][2];
#pragma unroll
        for (int ci = 0; ci < 2; ++ci)
#pragma unroll
            for (int p = 0; p < 2; ++p) acc[ci][p] = (f32x4){0.f, 0.f, 0.f, 0.f};

        const int arow = mt * 16 + (lane & 15);
#pragma unroll
        for (int ks = 0; ks < 4; ++ks) {
            s16x8 a0 = *(const s16x8*)&A[0][arow * ASTR + ks * 32 + kq];
            s16x8 a1 = *(const s16x8*)&A[1][arow * ASTR + ks * 32 + kq];
#pragma unroll
            for (int ci = 0; ci < 2; ++ci) {
                acc[ci][0] = __builtin_amdgcn_mfma_f32_16x16x32_bf16(
                    a0, Bf[ci][0][ks], acc[ci][0], 0, 0, 0);
                acc[ci][1] = __builtin_amdgcn_mfma_f32_16x16x32_bf16(
                    a1, Bf[ci][1][ks], acc[ci][1], 0, 0, 0);
            }
        }

#pragma unroll
        for (int ci = 0; ci < 2; ++ci) {
            int oc = (wv + ci * 4) * 16 + (lane & 15);
#pragma unroll
            for (int r = 0; r < 4; ++r) {
                int node = n0 + mt * 16 + quad * 4 + r;
                if (node < N_NODES) {
                    float v = lrelu(acc[ci][0][r] + bb1[ci])
                            + lrelu(acc[ci][1][r] + bb2[ci]);
                    out[(size_t)node * D + oc] = v;
                }
            }
        }
    }
}

// ============== Tier-0 fallback fp32 GEMM =====================================
__global__ __launch_bounds__(256) void gemm_kernel(
    const float* __restrict__ x, const float* __restrict__ h,
    const float* __restrict__ W1, const float* __restrict__ b1,
    const float* __restrict__ W2, const float* __restrict__ b2,
    float* __restrict__ out) {
    __shared__ float Aadd[32 * AP];
    __shared__ float Amul[32 * AP];
    const int n0 = blockIdx.x * 32;
    const int t = threadIdx.x;
#pragma unroll
    for (int i = 0; i < 4; ++i) {
        int fi = t + i * 256;
        int row = fi >> 5;
        int c4 = fi & 31;
        float4 xv = ((const float4*)(x + (size_t)(n0 + row) * D))[c4];
        float4 hv = ((const float4*)(h + (size_t)(n0 + row) * D))[c4];
        float4 av = make_float4(xv.x + hv.x, xv.y + hv.y, xv.z + hv.z, xv.w + hv.w);
        float4 mv = make_float4(xv.x * hv.x, xv.y * hv.y, xv.z * hv.z, xv.w * hv.w);
        *((float4*)&Aadd[row * AP + c4 * 4]) = av;
        *((float4*)&Amul[row * AP + c4 * 4]) = mv;
    }
    __syncthreads();
    const int m0 = (t >> 5) * 4;
    const int o0 = (t & 31) * 4;
    float acc1[4][4];
    float acc2[4][4];
#pragma unroll
    for (int i = 0; i < 4; ++i)
#pragma unroll
        for (int j = 0; j < 4; ++j) { acc1[i][j] = 0.0f; acc2[i][j] = 0.0f; }
#pragma unroll 4
    for (int d = 0; d < D; d += 4) {
        float4 a[4], m[4], w1[4], w2[4];
#pragma unroll
        for (int i = 0; i < 4; ++i) a[i] = *(const float4*)&Aadd[(m0 + i) * AP + d];
#pragma unroll
        for (int i = 0; i < 4; ++i) m[i] = *(const float4*)&Amul[(m0 + i) * AP + d];
#pragma unroll
        for (int j = 0; j < 4; ++j) w1[j] = *(const float4*)&W1[(size_t)(o0 + j) * D + d];
#pragma unroll
        for (int j = 0; j < 4; ++j) w2[j] = *(const float4*)&W2[(size_t)(o0 + j) * D + d];
#pragma unroll
        for (int i = 0; i < 4; ++i)
#pragma unroll
            for (int j = 0; j < 4; ++j) {
                acc1[i][j] += a[i].x * w1[j].x + a[i].y * w1[j].y
                            + a[i].z * w1[j].z + a[i].w * w1[j].w;
                acc2[i][j] += m[i].x * w2[j].x + m[i].y * w2[j].y
                            + m[i].z * w2[j].z + m[i].w * w2[j].w;
            }
    }
#pragma unroll
    for (int i = 0; i < 4; ++i) {
        float4 r;
        float v1, v2;
        v1 = lrelu(acc1[i][0] + b1[o0 + 0]); v2 = lrelu(acc2[i][0] + b2[o0 + 0]); r.x = v1 + v2;
        v1 = lrelu(acc1[i][1] + b1[o0 + 1]); v2 = lrelu(acc2[i][1] + b2[o0 + 1]); r.y = v1 + v2;
        v1 = lrelu(acc1[i][2] + b1[o0 + 2]); v2 = lrelu(acc2[i][2] + b2[o0 + 2]); r.z = v1 + v2;
        v1 = lrelu(acc1[i][3] + b1[o0 + 3]); v2 = lrelu(acc2[i][3] + b2[o0 + 3]); r.w = v1 + v2;
        ((float4*)(out + (size_t)(n0 + m0 + i) * D))[t & 31] = r;
    }
}

extern "C" void kernel_launch(void* const* d_in, const int* in_sizes, int n_in,
                              void* d_out, int out_size, void* d_ws, size_t ws_size,
                              hipStream_t stream) {
    const float* x   = (const float*)d_in[0];
    const int*   src = (const int*)d_in[1];
    const int*   dst = (const int*)d_in[2];
    const float* ea  = (const float*)d_in[3];
    const float* W1  = (const float*)d_in[4];
    const float* b1  = (const float*)d_in[5];
    const float* W2  = (const float*)d_in[6];
    const float* b2  = (const float*)d_in[7];
    float* out = (float*)d_out;

    auto align256 = [](size_t v) { return (v + 255) & ~(size_t)255; };

    const size_t SZ_WSWZ = 2 * 4 * 8 * 64 * 8 * sizeof(unsigned short);   // 64 KB
    const size_t SZ_OFF  = (size_t)(N_NODES + 1) * sizeof(int);
    const size_t SZ_BSUM = 512 * sizeof(int);
    const size_t SZ_RANK = (size_t)E_EDGES;                               // u8, 1.6 MB
    const size_t SZ_CSR  = (size_t)E_EDGES * sizeof(int2);                // 12.8 MB
    const size_t SZ_XBF  = (size_t)N_NODES * D * sizeof(unsigned short);  // 25.6 MB

    // Layout computed for a given counter stride (16 = padded, 1 = compact).
    struct Lay { size_t o_wswz, o_cnt, o_off, o_bsum, o_rank, o_csr, o_xbf,
                 need_fused, need_t1, sz_cnt; };
    auto mk = [&](int stride) {
        Lay L;
        L.sz_cnt = (size_t)N_NODES * stride * sizeof(int);
        L.o_wswz = 0;
        L.o_cnt  = L.o_wswz + align256(SZ_WSWZ);
        L.o_off  = L.o_cnt + align256(L.sz_cnt);
        L.o_bsum = L.o_off + align256(SZ_OFF);
        L.o_rank = L.o_bsum + align256(SZ_BSUM);
        L.o_csr  = L.o_rank + align256(SZ_RANK);
        L.o_xbf  = L.o_csr + align256(SZ_CSR);
        L.need_t1 = L.o_xbf;                       // csr path w/o xbf
        L.need_fused = L.o_xbf + align256(SZ_XBF); // + bf16 x table
        return L;
    };

    Lay L16 = mk(16), L1 = mk(1);
    int stride;
    Lay L;
    bool fused_ok, t1_ok;
    if (ws_size >= L16.need_fused)      { stride = 16; L = L16; fused_ok = true;  t1_ok = true; }
    else if (ws_size >= L1.need_fused)  { stride = 1;  L = L1;  fused_ok = true;  t1_ok = true; }
    else if (ws_size >= L1.need_t1)     { stride = 1;  L = L1;  fused_ok = false; t1_ok = true; }
    else                                { stride = 1;  L = L1;  fused_ok = false; t1_ok = false; }

    const int NB_E = (E_EDGES + 255) / 256;
    const int NB_N = (N_NODES + 255) / 256;

    char* ws = (char*)d_ws;
    unsigned short* Wswz = (unsigned short*)(ws + L.o_wswz);
    int*   cnt  = (int*)(ws + L.o_cnt);
    int*   off  = (int*)(ws + L.o_off);
    int*   bsum = (int*)(ws + L.o_bsum);
    unsigned char* rank = (unsigned char*)(ws + L.o_rank);
    int2*  csr  = (int2*)(ws + L.o_csr);
    unsigned short* xbf = (unsigned short*)(ws + L.o_xbf);

    if (t1_ok) {
        hipMemsetAsync(cnt, 0, L.sz_cnt, stream);
        if (fused_ok)
            xconv_kernel<<<(N_NODES * D / 8 + 255) / 256, 256, 0, stream>>>(x, xbf);
        hist_kernel<<<NB_E, 256, 0, stream>>>(dst, cnt, rank, E_EDGES, stride);
        scanA_kernel<<<NB_N, 256, 0, stream>>>(cnt, off, bsum, N_NODES, stride);
        scanB_kernel<<<1, 512, 0, stream>>>(bsum, NB_N);
        scanC_kernel<<<NB_N, 256, 0, stream>>>(bsum, off, N_NODES, E_EDGES);
        fill_kernel<<<NB_E, 256, 0, stream>>>(src, dst, ea, off, rank, csr, E_EDGES);
        wconv_kernel<<<16, 256, 0, stream>>>(W1, W2, Wswz);

        int blocks = (N_NODES + 63) / 64;  // 1563
        if (fused_ok) {
            fused_gemm_kernel<<<blocks, 256, 0, stream>>>(xbf, csr, off, Wswz,
                                                          b1, b2, out);
        } else {
            // tier 1: gather to h (aliases out), then MFMA gemm reads h
            float* h = out;
            gather_f32_kernel<<<N_NODES / 4, 256, 0, stream>>>(x, csr, off, h);
            mfma_gemm_kernel<<<blocks, 256, 0, stream>>>(x, h, Wswz, b1, b2, out);
        }
    } else {
        // Tier 0: atomic scatter + fp32 gemm (R1-proven)
        float* h = out;
        hipMemsetAsync(h, 0, (size_t)N_NODES * D * sizeof(float), stream);
        int total = E_EDGES * 32;
        scatter_kernel<<<(total + 255) / 256, 256, 0, stream>>>(x, src, dst, ea,
                                                                h, E_EDGES);
        gemm_kernel<<<N_NODES / 32, 256, 0, stream>>>(x, h, W1, b1, W2, b2, out);
    }
}

// Round 6
// 305.804 us; speedup vs baseline: 1.2332x; 1.2332x over previous
//
#include <hip/hip_runtime.h>

#define N_NODES 100000
#define E_EDGES 1600000
#define D 128
#define AP 132   // padded LDS pitch for fallback fp32 gemm
#define ASTR 136 // bf16 elems per LDS row in MFMA gemm (272 B = 17*16, keeps 16B align)

typedef short s16x8 __attribute__((ext_vector_type(8)));
typedef unsigned short u16x8 __attribute__((ext_vector_type(8)));
typedef float f32x4 __attribute__((ext_vector_type(4)));

__device__ __forceinline__ unsigned short f2bf(float f) {
    union { float f; unsigned u; } v;
    v.f = f;
    unsigned r = v.u + 0x7FFFu + ((v.u >> 16) & 1u);  // RNE
    return (unsigned short)(r >> 16);
}

__device__ __forceinline__ float bf2f(unsigned short u) {
    union { unsigned u; float f; } v;
    v.u = ((unsigned)u) << 16;
    return v.f;
}

__device__ __forceinline__ float lrelu(float v) {
    return v >= 0.0f ? v : 0.01f * v;
}

// ====== prep: hist (blocks 0..6249) ∥ xconv (6250..12499) ∥ wconv (12500..12515)
__global__ __launch_bounds__(256) void prep_kernel(
    const int* __restrict__ dst, int* __restrict__ cnt,
    unsigned char* __restrict__ rank, int stride,
    const float* __restrict__ x, unsigned short* __restrict__ xbf, int do_xconv,
    const float* __restrict__ W1, const float* __restrict__ W2,
    unsigned short* __restrict__ Wswz) {
    int b = blockIdx.x;
    int t = threadIdx.x;
    if (b < 6250) {
        // hist + rank (E = 6250*256 exactly). Padded counters (stride ints)
        // put each node's counter in its own 64B sector -> parallel atomics.
        int e = b * 256 + t;
        rank[e] = (unsigned char)atomicAdd(&cnt[(size_t)dst[e] * stride], 1);
    } else if (b < 12500) {
        if (!do_xconv) return;
        int idx = (b - 6250) * 256 + t;   // N*D/8 = 6250*256 exactly
        const float4* xp = (const float4*)(x) + (size_t)idx * 2;
        float4 a = xp[0], bb = xp[1];
        u16x8 o;
        o[0] = f2bf(a.x);  o[1] = f2bf(a.y);  o[2] = f2bf(a.z);  o[3] = f2bf(a.w);
        o[4] = f2bf(bb.x); o[5] = f2bf(bb.y); o[6] = f2bf(bb.z); o[7] = f2bf(bb.w);
        ((u16x8*)(xbf))[idx] = o;
    } else {
        int tid = (b - 12500) * 256 + t;
        if (tid >= 2 * 4 * 8 * 64) return;
        int lane = tid & 63;
        int ct   = (tid >> 6) & 7;
        int ks   = (tid >> 9) & 3;
        int mat  = tid >> 11;
        const float* W = mat ? W2 : W1;
        int o  = ct * 16 + (lane & 15);
        int k0 = ks * 32 + (lane >> 4) * 8;
        const float* sp = W + (size_t)o * D + k0;
        u16x8 w;
#pragma unroll
        for (int j = 0; j < 8; ++j) w[j] = f2bf(sp[j]);
        ((u16x8*)(Wswz))[tid] = w;
    }
}

// ====== scans ================================================================
__global__ __launch_bounds__(256) void scanA_kernel(
    const int* __restrict__ cnt, int* __restrict__ excl,
    int* __restrict__ bsum, int n, int stride) {
    __shared__ int tmp[256];
    int gid = blockIdx.x * 256 + threadIdx.x;
    int v = (gid < n) ? cnt[(size_t)gid * stride] : 0;
    tmp[threadIdx.x] = v;
    __syncthreads();
    for (int ofs = 1; ofs < 256; ofs <<= 1) {
        int t = (threadIdx.x >= ofs) ? tmp[threadIdx.x - ofs] : 0;
        __syncthreads();
        tmp[threadIdx.x] += t;
        __syncthreads();
    }
    int incl = tmp[threadIdx.x];
    if (gid < n) excl[gid] = incl - v;
    if (threadIdx.x == 255) bsum[blockIdx.x] = incl;
}

__global__ __launch_bounds__(512) void scanB_kernel(int* __restrict__ bsum, int nb) {
    __shared__ int tmp[512];
    int v = (threadIdx.x < nb) ? bsum[threadIdx.x] : 0;
    tmp[threadIdx.x] = v;
    __syncthreads();
    for (int ofs = 1; ofs < 512; ofs <<= 1) {
        int t = (threadIdx.x >= ofs) ? tmp[threadIdx.x - ofs] : 0;
        __syncthreads();
        tmp[threadIdx.x] += t;
        __syncthreads();
    }
    if (threadIdx.x < nb) bsum[threadIdx.x] = tmp[threadIdx.x] - v;
}

// ====== fillC: csr fill (atomic-free) + final off[] in one pass ===============
__global__ __launch_bounds__(256) void fillC_kernel(
    const int* __restrict__ src, const int* __restrict__ dst,
    const float* __restrict__ ea, const int* __restrict__ excl,
    const int* __restrict__ bsum, const unsigned char* __restrict__ rank,
    int2* __restrict__ csr, int* __restrict__ off) {
    int gid = blockIdx.x * 256 + threadIdx.x;   // 6250*256 = E exactly
    int d = dst[gid];
    int pos = excl[d] + bsum[d >> 8] + (int)rank[gid];
    csr[pos] = make_int2(src[gid], __float_as_int(ea[gid]));
    if (gid < N_NODES) off[gid] = excl[gid] + bsum[gid >> 8];
    else if (gid == N_NODES) off[N_NODES] = E_EDGES;
}

// ====== gather16: 16 lanes/edge, ushort8 loads, 4 edges in flight/wave ========
// HBF16: write h as bf16 (hbf); else fp32 (hf, aliases out).
template <bool HBF16>
__global__ __launch_bounds__(256) void gather16_kernel(
    const unsigned short* __restrict__ xbf, const int2* __restrict__ csr,
    const int* __restrict__ off, unsigned short* __restrict__ hbf,
    float* __restrict__ hf) {
    int node = blockIdx.x * 4 + (threadIdx.x >> 6);   // 25000*4 = N exactly
    int lane = threadIdx.x & 63;
    int q = lane >> 4;       // quarter: which edge of 4 in flight
    int li = lane & 15;      // dims [li*8, li*8+8)
    int beg = off[node];
    int end = off[node + 1];

    float a0[8], a1[8];
#pragma unroll
    for (int d = 0; d < 8; ++d) { a0[d] = 0.f; a1[d] = 0.f; }

    int i = beg + q;
    for (; i + 4 < end; i += 8) {
        int2 p0 = csr[i];
        int2 p1 = csr[i + 4];
        float w0 = __int_as_float(p0.y);
        float w1 = __int_as_float(p1.y);
        u16x8 v0 = ((const u16x8*)(xbf + (size_t)p0.x * D))[li];
        u16x8 v1 = ((const u16x8*)(xbf + (size_t)p1.x * D))[li];
#pragma unroll
        for (int d = 0; d < 8; ++d) {
            a0[d] += w0 * bf2f(v0[d]);
            a1[d] += w1 * bf2f(v1[d]);
        }
    }
    if (i < end) {
        int2 p0 = csr[i];
        float w0 = __int_as_float(p0.y);
        u16x8 v0 = ((const u16x8*)(xbf + (size_t)p0.x * D))[li];
#pragma unroll
        for (int d = 0; d < 8; ++d) a0[d] += w0 * bf2f(v0[d]);
    }
#pragma unroll
    for (int d = 0; d < 8; ++d) a0[d] += a1[d];
    // combine 4 quarters (butterfly over lane bits 4,5)
#pragma unroll
    for (int d = 0; d < 8; ++d) a0[d] += __shfl_xor(a0[d], 16);
#pragma unroll
    for (int d = 0; d < 8; ++d) a0[d] += __shfl_xor(a0[d], 32);

    if (q == 0) {
        if (HBF16) {
            u16x8 o;
#pragma unroll
            for (int d = 0; d < 8; ++d) o[d] = f2bf(a0[d]);
            ((u16x8*)(hbf + (size_t)node * D))[li] = o;
        } else {
            float4 lo = make_float4(a0[0], a0[1], a0[2], a0[3]);
            float4 hi = make_float4(a0[4], a0[5], a0[6], a0[7]);
            ((float4*)(hf + (size_t)node * D))[li * 2 + 0] = lo;
            ((float4*)(hf + (size_t)node * D))[li * 2 + 1] = hi;
        }
    }
}

// ====== MFMA GEMM from xbf (+ hbf bf16 or h fp32) =============================
template <bool HBF16>
__global__ __launch_bounds__(256, 4) void mfma_gemm_bfh_kernel(
    const unsigned short* __restrict__ xbf, const unsigned short* __restrict__ hbf,
    const float* __restrict__ hf, const unsigned short* __restrict__ Wswz,
    const float* __restrict__ b1, const float* __restrict__ b2,
    float* __restrict__ out) {
    __shared__ unsigned short A[2][64 * ASTR];

    const int n0 = blockIdx.x * 64;
    const int t = threadIdx.x;
    const int lane = t & 63;
    const int wv = t >> 6;

    // Stage: 1024 ushort8 slots (64 rows x 16), 4 per thread.
#pragma unroll
    for (int i = 0; i < 4; ++i) {
        int s = t + i * 256;
        int row = s >> 4;
        int c8 = s & 15;
        int srcrow = n0 + row;
        if (srcrow >= N_NODES) srcrow = N_NODES - 1;  // tail clamp (write-guarded)
        u16x8 xu = ((const u16x8*)(xbf + (size_t)srcrow * D))[c8];
        float hd[8];
        if (HBF16) {
            u16x8 hu = ((const u16x8*)(hbf + (size_t)srcrow * D))[c8];
#pragma unroll
            for (int j = 0; j < 8; ++j) hd[j] = bf2f(hu[j]);
        } else {
            float4 h0 = ((const float4*)(hf + (size_t)srcrow * D))[c8 * 2 + 0];
            float4 h1 = ((const float4*)(hf + (size_t)srcrow * D))[c8 * 2 + 1];
            hd[0] = h0.x; hd[1] = h0.y; hd[2] = h0.z; hd[3] = h0.w;
            hd[4] = h1.x; hd[5] = h1.y; hd[6] = h1.z; hd[7] = h1.w;
        }
        u16x8 av, mv;
#pragma unroll
        for (int j = 0; j < 8; ++j) {
            float xv = bf2f(xu[j]);
            av[j] = f2bf(xv + hd[j]);
            mv[j] = f2bf(xv * hd[j]);
        }
        *(u16x8*)&A[0][row * ASTR + c8 * 8] = av;
        *(u16x8*)&A[1][row * ASTR + c8 * 8] = mv;
    }

    // Persistent B fragments + biases.
    s16x8 Bf[2][2][4];
    float bb1[2], bb2[2];
#pragma unroll
    for (int ci = 0; ci < 2; ++ci) {
        int ct = wv + ci * 4;
        bb1[ci] = b1[ct * 16 + (lane & 15)];
        bb2[ci] = b2[ct * 16 + (lane & 15)];
#pragma unroll
        for (int mat = 0; mat < 2; ++mat)
#pragma unroll
            for (int ks = 0; ks < 4; ++ks)
                Bf[ci][mat][ks] = *(const s16x8*)(
                    Wswz + ((size_t)(((mat * 4 + ks) * 8 + ct) * 64 + lane)) * 8);
    }

    __syncthreads();

    const int quad = lane >> 4;
    const int kq = quad * 8;

#pragma unroll
    for (int mt = 0; mt < 4; ++mt) {
        f32x4 acc[2][2];
#pragma unroll
        for (int ci = 0; ci < 2; ++ci)
#pragma unroll
            for (int p = 0; p < 2; ++p) acc[ci][p] = (f32x4){0.f, 0.f, 0.f, 0.f};

        const int arow = mt * 16 + (lane & 15);
#pragma unroll
        for (int ks = 0; ks < 4; ++ks) {
            s16x8 aa0 = *(const s16x8*)&A[0][arow * ASTR + ks * 32 + kq];
            s16x8 aa1 = *(const s16x8*)&A[1][arow * ASTR + ks * 32 + kq];
#pragma unroll
            for (int ci = 0; ci < 2; ++ci) {
                acc[ci][0] = __builtin_amdgcn_mfma_f32_16x16x32_bf16(
                    aa0, Bf[ci][0][ks], acc[ci][0], 0, 0, 0);
                acc[ci][1] = __builtin_amdgcn_mfma_f32_16x16x32_bf16(
                    aa1, Bf[ci][1][ks], acc[ci][1], 0, 0, 0);
            }
        }

        // C/D layout: col=lane&15, row=quad*4+reg (m89-verified).
#pragma unroll
        for (int ci = 0; ci < 2; ++ci) {
            int oc = (wv + ci * 4) * 16 + (lane & 15);
#pragma unroll
            for (int r = 0; r < 4; ++r) {
                int node = n0 + mt * 16 + quad * 4 + r;
                if (node < N_NODES) {
                    float v = lrelu(acc[ci][0][r] + bb1[ci])
                            + lrelu(acc[ci][1][r] + bb2[ci]);
                    out[(size_t)node * D + oc] = v;
                }
            }
        }
    }
}

// ====== T1 fallback: fp32 gather + fp32-input MFMA gemm =======================
__global__ __launch_bounds__(256) void gather_f32_kernel(
    const float* __restrict__ x, const int2* __restrict__ csr,
    const int* __restrict__ off, float* __restrict__ h) {
    int node = blockIdx.x * 4 + (threadIdx.x >> 6);
    int lane = threadIdx.x & 63;
    int beg = off[node];
    int end = off[node + 1];
    float2 acc0 = make_float2(0.f, 0.f);
    float2 acc1 = make_float2(0.f, 0.f);
    int e = beg;
    for (; e + 1 < end; e += 2) {
        int2 p0 = csr[e];
        int2 p1 = csr[e + 1];
        float a0 = __int_as_float(p0.y);
        float a1 = __int_as_float(p1.y);
        float2 v0 = ((const float2*)(x + (size_t)p0.x * D))[lane];
        float2 v1 = ((const float2*)(x + (size_t)p1.x * D))[lane];
        acc0.x += a0 * v0.x; acc0.y += a0 * v0.y;
        acc1.x += a1 * v1.x; acc1.y += a1 * v1.y;
    }
    if (e < end) {
        int2 p0 = csr[e];
        float a0 = __int_as_float(p0.y);
        float2 v0 = ((const float2*)(x + (size_t)p0.x * D))[lane];
        acc0.x += a0 * v0.x; acc0.y += a0 * v0.y;
    }
    acc0.x += acc1.x; acc0.y += acc1.y;
    ((float2*)(h + (size_t)node * D))[lane] = acc0;
}

__global__ __launch_bounds__(256, 4) void mfma_gemm_t1_kernel(
    const float* __restrict__ xf, const float* __restrict__ h,
    const unsigned short* __restrict__ Wswz,
    const float* __restrict__ b1, const float* __restrict__ b2,
    float* __restrict__ out) {
    __shared__ unsigned short A[2][64 * ASTR];
    const int n0 = blockIdx.x * 64;
    const int t = threadIdx.x;
    const int lane = t & 63;
    const int wv = t >> 6;
#pragma unroll
    for (int i = 0; i < 8; ++i) {
        int s = t + i * 256;
        int row = s >> 5;
        int c4 = s & 31;
        int srcrow = n0 + row;
        if (srcrow >= N_NODES) srcrow = N_NODES - 1;
        float4 xv = ((const float4*)(xf + (size_t)srcrow * D))[c4];
        float4 hv = ((const float4*)(h + (size_t)srcrow * D))[c4];
        ushort4 av, mv;
        av.x = f2bf(xv.x + hv.x); av.y = f2bf(xv.y + hv.y);
        av.z = f2bf(xv.z + hv.z); av.w = f2bf(xv.w + hv.w);
        mv.x = f2bf(xv.x * hv.x); mv.y = f2bf(xv.y * hv.y);
        mv.z = f2bf(xv.z * hv.z); mv.w = f2bf(xv.w * hv.w);
        *(ushort4*)&A[0][row * ASTR + c4 * 4] = av;
        *(ushort4*)&A[1][row * ASTR + c4 * 4] = mv;
    }
    s16x8 Bf[2][2][4];
    float bb1[2], bb2[2];
#pragma unroll
    for (int ci = 0; ci < 2; ++ci) {
        int ct = wv + ci * 4;
        bb1[ci] = b1[ct * 16 + (lane & 15)];
        bb2[ci] = b2[ct * 16 + (lane & 15)];
#pragma unroll
        for (int mat = 0; mat < 2; ++mat)
#pragma unroll
            for (int ks = 0; ks < 4; ++ks)
                Bf[ci][mat][ks] = *(const s16x8*)(
                    Wswz + ((size_t)(((mat * 4 + ks) * 8 + ct) * 64 + lane)) * 8);
    }
    __syncthreads();
    const int quad = lane >> 4;
    const int kq = quad * 8;
#pragma unroll
    for (int mt = 0; mt < 4; ++mt) {
        f32x4 acc[2][2];
#pragma unroll
        for (int ci = 0; ci < 2; ++ci)
#pragma unroll
            for (int p = 0; p < 2; ++p) acc[ci][p] = (f32x4){0.f, 0.f, 0.f, 0.f};
        const int arow = mt * 16 + (lane & 15);
#pragma unroll
        for (int ks = 0; ks < 4; ++ks) {
            s16x8 aa0 = *(const s16x8*)&A[0][arow * ASTR + ks * 32 + kq];
            s16x8 aa1 = *(const s16x8*)&A[1][arow * ASTR + ks * 32 + kq];
#pragma unroll
            for (int ci = 0; ci < 2; ++ci) {
                acc[ci][0] = __builtin_amdgcn_mfma_f32_16x16x32_bf16(
                    aa0, Bf[ci][0][ks], acc[ci][0], 0, 0, 0);
                acc[ci][1] = __builtin_amdgcn_mfma_f32_16x16x32_bf16(
                    aa1, Bf[ci][1][ks], acc[ci][1], 0, 0, 0);
            }
        }
#pragma unroll
        for (int ci = 0; ci < 2; ++ci) {
            int oc = (wv + ci * 4) * 16 + (lane & 15);
#pragma unroll
            for (int r = 0; r < 4; ++r) {
                int node = n0 + mt * 16 + quad * 4 + r;
                if (node < N_NODES) {
                    float v = lrelu(acc[ci][0][r] + bb1[ci])
                            + lrelu(acc[ci][1][r] + bb2[ci]);
                    out[(size_t)node * D + oc] = v;
                }
            }
        }
    }
}

// ====== T0 fallback: atomic scatter + fp32 gemm ===============================
__global__ __launch_bounds__(256) void scatter_kernel(
    const float* __restrict__ x, const int* __restrict__ src,
    const int* __restrict__ dst, const float* __restrict__ ea,
    float* __restrict__ h, int E) {
    int idx = blockIdx.x * 256 + threadIdx.x;
    int e = idx >> 5;
    int lane = idx & 31;
    if (e >= E) return;
    int s = src[e];
    int d = dst[e];
    float a = ea[e];
    float4 v = ((const float4*)(x + (size_t)s * D))[lane];
    float* hp = h + (size_t)d * D + lane * 4;
    atomicAdd(hp + 0, a * v.x);
    atomicAdd(hp + 1, a * v.y);
    atomicAdd(hp + 2, a * v.z);
    atomicAdd(hp + 3, a * v.w);
}

__global__ __launch_bounds__(256) void gemm_kernel(
    const float* __restrict__ x, const float* __restrict__ h,
    const float* __restrict__ W1, const float* __restrict__ b1,
    const float* __restrict__ W2, const float* __restrict__ b2,
    float* __restrict__ out) {
    __shared__ float Aadd[32 * AP];
    __shared__ float Amul[32 * AP];
    const int n0 = blockIdx.x * 32;
    const int t = threadIdx.x;
#pragma unroll
    for (int i = 0; i < 4; ++i) {
        int fi = t + i * 256;
        int row = fi >> 5;
        int c4 = fi & 31;
        float4 xv = ((const float4*)(x + (size_t)(n0 + row) * D))[c4];
        float4 hv = ((const float4*)(h + (size_t)(n0 + row) * D))[c4];
        float4 av = make_float4(xv.x + hv.x, xv.y + hv.y, xv.z + hv.z, xv.w + hv.w);
        float4 mv = make_float4(xv.x * hv.x, xv.y * hv.y, xv.z * hv.z, xv.w * hv.w);
        *((float4*)&Aadd[row * AP + c4 * 4]) = av;
        *((float4*)&Amul[row * AP + c4 * 4]) = mv;
    }
    __syncthreads();
    const int m0 = (t >> 5) * 4;
    const int o0 = (t & 31) * 4;
    float acc1[4][4];
    float acc2[4][4];
#pragma unroll
    for (int i = 0; i < 4; ++i)
#pragma unroll
        for (int j = 0; j < 4; ++j) { acc1[i][j] = 0.0f; acc2[i][j] = 0.0f; }
#pragma unroll 4
    for (int d = 0; d < D; d += 4) {
        float4 a[4], m[4], w1[4], w2[4];
#pragma unroll
        for (int i = 0; i < 4; ++i) a[i] = *(const float4*)&Aadd[(m0 + i) * AP + d];
#pragma unroll
        for (int i = 0; i < 4; ++i) m[i] = *(const float4*)&Amul[(m0 + i) * AP + d];
#pragma unroll
        for (int j = 0; j < 4; ++j) w1[j] = *(const float4*)&W1[(size_t)(o0 + j) * D + d];
#pragma unroll
        for (int j = 0; j < 4; ++j) w2[j] = *(const float4*)&W2[(size_t)(o0 + j) * D + d];
#pragma unroll
        for (int i = 0; i < 4; ++i)
#pragma unroll
            for (int j = 0; j < 4; ++j) {
                acc1[i][j] += a[i].x * w1[j].x + a[i].y * w1[j].y
                            + a[i].z * w1[j].z + a[i].w * w1[j].w;
                acc2[i][j] += m[i].x * w2[j].x + m[i].y * w2[j].y
                            + m[i].z * w2[j].z + m[i].w * w2[j].w;
            }
    }
#pragma unroll
    for (int i = 0; i < 4; ++i) {
        float4 r;
        float v1, v2;
        v1 = lrelu(acc1[i][0] + b1[o0 + 0]); v2 = lrelu(acc2[i][0] + b2[o0 + 0]); r.x = v1 + v2;
        v1 = lrelu(acc1[i][1] + b1[o0 + 1]); v2 = lrelu(acc2[i][1] + b2[o0 + 1]); r.y = v1 + v2;
        v1 = lrelu(acc1[i][2] + b1[o0 + 2]); v2 = lrelu(acc2[i][2] + b2[o0 + 2]); r.z = v1 + v2;
        v1 = lrelu(acc1[i][3] + b1[o0 + 3]); v2 = lrelu(acc2[i][3] + b2[o0 + 3]); r.w = v1 + v2;
        ((float4*)(out + (size_t)(n0 + m0 + i) * D))[t & 31] = r;
    }
}

extern "C" void kernel_launch(void* const* d_in, const int* in_sizes, int n_in,
                              void* d_out, int out_size, void* d_ws, size_t ws_size,
                              hipStream_t stream) {
    const float* x   = (const float*)d_in[0];
    const int*   src = (const int*)d_in[1];
    const int*   dst = (const int*)d_in[2];
    const float* ea  = (const float*)d_in[3];
    const float* W1  = (const float*)d_in[4];
    const float* b1  = (const float*)d_in[5];
    const float* W2  = (const float*)d_in[6];
    const float* b2  = (const float*)d_in[7];
    float* out = (float*)d_out;

    auto align256 = [](size_t v) { return (v + 255) & ~(size_t)255; };

    const size_t SZ_WSWZ = 2 * 4 * 8 * 64 * 8 * sizeof(unsigned short);   // 64 KB
    const size_t SZ_OFF  = (size_t)(N_NODES + 1) * sizeof(int);
    const size_t SZ_EXCL = (size_t)N_NODES * sizeof(int);
    const size_t SZ_BSUM = 512 * sizeof(int);
    const size_t SZ_RANK = (size_t)E_EDGES;                               // u8, 1.6 MB
    const size_t SZ_CSR  = (size_t)E_EDGES * sizeof(int2);                // 12.8 MB
    const size_t SZ_XBF  = (size_t)N_NODES * D * sizeof(unsigned short);  // 25.6 MB
    const size_t SZ_HBF  = SZ_XBF;                                        // 25.6 MB

    struct Lay { size_t o_wswz, o_cnt, o_off, o_excl, o_bsum, o_rank, o_csr,
                 o_xbf, o_hbf, need_t1, need_t2, need_t3, sz_cnt; };
    auto mk = [&](int stride) {
        Lay L;
        L.sz_cnt = (size_t)N_NODES * stride * sizeof(int);
        L.o_wswz = 0;
        L.o_cnt  = L.o_wswz + align256(SZ_WSWZ);
        L.o_off  = L.o_cnt + align256(L.sz_cnt);
        L.o_excl = L.o_off + align256(SZ_OFF);
        L.o_bsum = L.o_excl + align256(SZ_EXCL);
        L.o_rank = L.o_bsum + align256(SZ_BSUM);
        L.o_csr  = L.o_rank + align256(SZ_RANK);
        L.o_xbf  = L.o_csr + align256(SZ_CSR);
        L.o_hbf  = L.o_xbf + align256(SZ_XBF);
        L.need_t1 = L.o_xbf;                       // CSR path, no xbf
        L.need_t2 = L.o_hbf;                       // + xbf (h fp32 in out)
        L.need_t3 = L.o_hbf + align256(SZ_HBF);    // + hbf
        return L;
    };

    Lay L16 = mk(16), L1 = mk(1);
    // Tier select: prefer padded counters and the bf16 h path.
    int tier;
    Lay L;
    int stride;
    if (ws_size >= L16.need_t3)      { tier = 3; L = L16; stride = 16; }
    else if (ws_size >= L16.need_t2) { tier = 2; L = L16; stride = 16; }
    else if (ws_size >= L1.need_t2)  { tier = 2; L = L1;  stride = 1; }
    else if (ws_size >= L1.need_t1)  { tier = 1; L = L1;  stride = 1; }
    else                             { tier = 0; L = L1;  stride = 1; }

    char* ws = (char*)d_ws;
    unsigned short* Wswz = (unsigned short*)(ws + L.o_wswz);
    int*   cnt  = (int*)(ws + L.o_cnt);
    int*   off  = (int*)(ws + L.o_off);
    int*   excl = (int*)(ws + L.o_excl);
    int*   bsum = (int*)(ws + L.o_bsum);
    unsigned char* rank = (unsigned char*)(ws + L.o_rank);
    int2*  csr  = (int2*)(ws + L.o_csr);
    unsigned short* xbf = (unsigned short*)(ws + L.o_xbf);
    unsigned short* hbf = (unsigned short*)(ws + L.o_hbf);

    const int NB_E = 6250;   // E/256
    const int NB_N = (N_NODES + 255) / 256;  // 391
    const int GEMM_BLOCKS = (N_NODES + 63) / 64;  // 1563

    if (tier >= 1) {
        hipMemsetAsync(cnt, 0, L.sz_cnt, stream);
        prep_kernel<<<12516, 256, 0, stream>>>(dst, cnt, rank, stride,
                                               x, xbf, tier >= 2 ? 1 : 0,
                                               W1, W2, Wswz);
        scanA_kernel<<<NB_N, 256, 0, stream>>>(cnt, excl, bsum, N_NODES, stride);
        scanB_kernel<<<1, 512, 0, stream>>>(bsum, NB_N);
        fillC_kernel<<<NB_E, 256, 0, stream>>>(src, dst, ea, excl, bsum, rank,
                                               csr, off);
        if (tier == 3) {
            gather16_kernel<true><<<N_NODES / 4, 256, 0, stream>>>(xbf, csr, off,
                                                                   hbf, nullptr);
            mfma_gemm_bfh_kernel<true><<<GEMM_BLOCKS, 256, 0, stream>>>(
                xbf, hbf, nullptr, Wswz, b1, b2, out);
        } else if (tier == 2) {
            // h fp32 aliases out (R4-proven safe: blocks only read their own rows)
            float* h = out;
            gather16_kernel<false><<<N_NODES / 4, 256, 0, stream>>>(xbf, csr, off,
                                                                    nullptr, h);
            mfma_gemm_bfh_kernel<false><<<GEMM_BLOCKS, 256, 0, stream>>>(
                xbf, nullptr, h, Wswz, b1, b2, out);
        } else {  // tier 1: no xbf
            float* h = out;
            gather_f32_kernel<<<N_NODES / 4, 256, 0, stream>>>(x, csr, off, h);
            mfma_gemm_t1_kernel<<<GEMM_BLOCKS, 256, 0, stream>>>(x, h, Wswz,
                                                                 b1, b2, out);
        }
    } else {
        float* h = out;
        hipMemsetAsync(h, 0, (size_t)N_NODES * D * sizeof(float), stream);
        int total = E_EDGES * 32;
        scatter_kernel<<<(total + 255) / 256, 256, 0, stream>>>(x, src, dst, ea,
                                                                h, E_EDGES);
        gemm_kernel<<<N_NODES / 32, 256, 0, stream>>>(x, h, W1, b1, W2, b2, out);
    }
}